// Round 8
// baseline (186.972 us; speedup 1.0000x reference)
//
#include <hip/hip_runtime.h>
#include <hip/hip_bf16.h>
#include <stdint.h>

#define T_TOK 2048
#define H_DIM 1024
#define E_NUM 8
#define I_DIM 512
#define KDOWN (E_NUM * I_DIM) /* 4096 */
#define EPSR 1e-8f

typedef short s16x8 __attribute__((ext_vector_type(8)));
typedef float f32x4 __attribute__((ext_vector_type(4)));

static __device__ __forceinline__ uint16_t f2bf(float f) {
    union { float f; uint32_t i; } v; v.f = f;
    uint32_t lsb = (v.i >> 16) & 1u;
    v.i += 0x7fffu + lsb;                    // round-to-nearest-even
    return (uint16_t)(v.i >> 16);
}

// async global->LDS DMA, 16B/lane; LDS dest = wave-uniform base + lane*16
static __device__ __forceinline__ void gll16(const void* g, void* l) {
    __builtin_amdgcn_global_load_lds(
        (const __attribute__((address_space(1))) void*)g,
        (__attribute__((address_space(3))) void*)l, 16, 0, 0);
}

// ------------- prep: weight transpose-cast + routing + out zero-fill -------------
// bid<3072: transpose (decoded as old grid (8,16,24)); 3072..3583: routing;
// 3584..4095: zero-fill of out[T][H] (enables the atomic split-K epilogue in down).
// wg/wu go to ONE interleaved big-B matrix wB[8192][1024]:
//   row(e,i,isU) = e*1024 + (i>>4)*32 + isU*16 + (i&15)
__global__ __launch_bounds__(256) void prep_kernel(
    const float* __restrict__ wg, const float* __restrict__ wu,
    const float* __restrict__ wd, uint16_t* __restrict__ wB,
    uint16_t* __restrict__ wdT,
    const float* __restrict__ x, const float* __restrict__ emb,
    const float* __restrict__ thr, float* __restrict__ scores_out,
    float* __restrict__ gates, uint16_t* __restrict__ xb,
    float* __restrict__ out0) {
    __shared__ union {
        float tile[64][69];   // 69: stride 68 was an 8-way bank conflict on col reads; 69 -> 2-way (free)
        struct { float semb[E_NUM * H_DIM]; float senorm[E_NUM]; } r;
    } sm;
    const int bid = blockIdx.x;
    const int tid = threadIdx.x;

    if (bid < 3072) {   // ---- transpose+cast part ----
        const int bz = bid >> 7, by = (bid >> 3) & 15, bx = bid & 7;
        const int g16 = tid >> 4, l16 = (tid & 15) * 4;
        if (bz < 16) {
            const int e = bz & 7;
            const int isU = (bz >= 8);
            const float* src = (isU ? wu : wg) + (long)e * H_DIM * I_DIM;
            const int r0 = by * 64, c0 = bx * 64;   // r0: h, c0: i
            #pragma unroll
            for (int it = 0; it < 4; ++it) {
                int r = it * 16 + g16;
                *(float4*)&sm.tile[r][l16] = *(const float4*)(src + (long)(r0 + r) * I_DIM + c0 + l16);
            }
            __syncthreads();
            #pragma unroll
            for (int it = 0; it < 4; ++it) {
                int oc = it * 16 + g16;
                int i = c0 + oc;
                ushort4 o;
                o.x = f2bf(sm.tile[l16 + 0][oc]);
                o.y = f2bf(sm.tile[l16 + 1][oc]);
                o.z = f2bf(sm.tile[l16 + 2][oc]);
                o.w = f2bf(sm.tile[l16 + 3][oc]);
                long rbig = ((long)e << 10) + ((i >> 4) << 5) + (isU << 4) + (i & 15);
                *(ushort4*)(wB + rbig * H_DIM + r0 + l16) = o;
            }
        } else {
            const int e = bz - 16;
            const float* src = wd + (long)e * I_DIM * H_DIM;
            uint16_t* dst = wdT + (long)e * I_DIM;    // wdT[h][e*512 + i]
            const int r0 = bx * 64, c0 = by * 64;
            #pragma unroll
            for (int it = 0; it < 4; ++it) {
                int r = it * 16 + g16;
                *(float4*)&sm.tile[r][l16] = *(const float4*)(src + (long)(r0 + r) * H_DIM + c0 + l16);
            }
            __syncthreads();
            #pragma unroll
            for (int it = 0; it < 4; ++it) {
                int oc = it * 16 + g16;
                ushort4 o;
                o.x = f2bf(sm.tile[l16 + 0][oc]);
                o.y = f2bf(sm.tile[l16 + 1][oc]);
                o.z = f2bf(sm.tile[l16 + 2][oc]);
                o.w = f2bf(sm.tile[l16 + 3][oc]);
                *(ushort4*)(dst + (long)(c0 + oc) * KDOWN + r0 + l16) = o;
            }
        }
        return;
    }
    if (bid >= 3584) {  // ---- zero-fill out[2048][1024] (16 KB per block) ----
        const int zb = bid - 3584;
        const float4 z = {0.f, 0.f, 0.f, 0.f};
        #pragma unroll
        for (int it = 0; it < 4; ++it)
            *(float4*)(out0 + (long)zb * 4096 + it * 1024 + tid * 4) = z;
        return;
    }
    // ---- routing part: cosine scores + masked softmax gates + bf16 cast of x ----
    const int rb = bid - 3072;
    const int lane = tid & 63;
    const int wave = tid >> 6;
    for (int i = tid; i < E_NUM * H_DIM; i += 256) sm.r.semb[i] = emb[i];
    __syncthreads();
    for (int e = wave; e < E_NUM; e += 4) {
        float s = 0.f;
        #pragma unroll
        for (int c = 0; c < 16; ++c) { float v = sm.r.semb[e * H_DIM + lane + 64 * c]; s += v * v; }
        #pragma unroll
        for (int off = 32; off; off >>= 1) s += __shfl_xor(s, off);
        if (lane == 0) sm.r.senorm[e] = fmaxf(sqrtf(s), EPSR);
    }
    __syncthreads();
    const int t = rb * 4 + wave;
    const float* xt = x + (long)t * H_DIM;
    uint16_t* xbt = xb + (long)t * H_DIM;
    float nrm = 0.f, dot[E_NUM];
    #pragma unroll
    for (int e = 0; e < E_NUM; ++e) dot[e] = 0.f;
    #pragma unroll
    for (int c = 0; c < 16; ++c) {
        float v = xt[lane + 64 * c];
        xbt[lane + 64 * c] = f2bf(v);
        nrm += v * v;
        #pragma unroll
        for (int e = 0; e < E_NUM; ++e) dot[e] += v * sm.r.semb[e * H_DIM + lane + 64 * c];
    }
    #pragma unroll
    for (int off = 32; off; off >>= 1) {
        nrm += __shfl_xor(nrm, off);
        #pragma unroll
        for (int e = 0; e < E_NUM; ++e) dot[e] += __shfl_xor(dot[e], off);
    }
    float xn = fmaxf(sqrtf(nrm), EPSR);
    float sc[E_NUM], sel[E_NUM];
    float msel = -1e30f, mall = -1e30f;
    int nsel = 0, arg = 0;
    #pragma unroll
    for (int e = 0; e < E_NUM; ++e) {
        sc[e] = dot[e] / (xn * sm.r.senorm[e]);
        float d = sc[e] - thr[e];
        sel[e] = (d > 0.f) ? 1.f : 0.f;                 // silu(d) > 0  <=>  d > 0
        if (d > 0.f) { nsel++; msel = fmaxf(msel, sc[e]); }
        if (sc[e] > mall) { mall = sc[e]; arg = e; }
    }
    float w[E_NUM], den = 0.f;
    #pragma unroll
    for (int e = 0; e < E_NUM; ++e) { w[e] = (sel[e] > 0.f) ? __expf(sc[e] - msel) : 0.f; den += w[e]; }
    if (lane == 0) {
        #pragma unroll
        for (int e = 0; e < E_NUM; ++e) {
            scores_out[t * E_NUM + e] = sc[e];
            gates[t * E_NUM + e] = (nsel > 0) ? (w[e] / den) : ((e == arg) ? 1.f : 0.f);
        }
    }
}

// ---------------- gate/up GEMM, 8-phase-class schedule (r4 structure, UNCHANGED) ----------------
// C[2048 x 8192] = xb @ wB^T, K=1024. 256 blocks x 512 thr (1 blk/CU), 8 waves 2Mx4N,
// per-wave 128x64 out. LDS 128KB = 4-deep ring of K=32 slots (A 256x32 + B 256x32).
// Per slot: 2 phases x 16 MFMA, 2 gll16 staged 3 slots ahead, COUNTED vmcnt(8)
// once per slot (never 0 in main loop, T4), raw s_barrier + setprio(1) around MFMA
// (T5). Per-phase barriers are LOAD-BEARING (r5: collapsing to 1 barrier/slot
// cost +7.6us, m196-consistent). Cross-session timing swings 42-58us with
// identical code (clock state) — judge by within-session A/B only.
__global__ __launch_bounds__(512, 2) void moe_gateup_kernel(
    const uint16_t* __restrict__ xb,    // [2048][1024]
    const uint16_t* __restrict__ wB,    // [8192][1024] interleaved g/u
    const float* __restrict__ gates,    // [2048][8]
    uint16_t* __restrict__ hmid) {      // [2048][4096] = [t][e*512+i]
    const int bid = blockIdx.x;
    const int xcd = bid & 7, j = bid >> 3;       // j 0..31
    const int by = xcd * 4 + (j >> 3);           // n-tile 0..31 (expert = by>>2)
    const int bx = j & 7;                        // t-tile 0..7
    const int t0 = bx * 256;
    const int n0 = by * 256;                     // B-row base
    const int e  = by >> 2;

    __shared__ uint16_t sA[4][256][32];          // 64 KB ring (A)
    __shared__ uint16_t sB[4][256][32];          // 64 KB ring (B)
    __shared__ float sGate[256];

    const int tid  = threadIdx.x;
    const int lane = tid & 63;
    const int wave = tid >> 6;                   // 0..7
    const int wm = wave >> 2, wn = wave & 3;     // 2M x 4N

    if (tid < 256) sGate[tid] = gates[(t0 + tid) * E_NUM + e];
    __syncthreads();   // sGate visible; full drain OK here (one-time, prologue)

    // staging: per (wave,half): 16 rows; lane l -> row l>>2, src chunk (l&3)^((l>>3)&3)
    const int lr = lane >> 2;
    const int cl = ((lane & 3) ^ ((lane >> 3) & 3)) * 8;
    const uint16_t* gA = xb + (long)(t0 + wave * 16 + lr) * H_DIM + cl;
    const uint16_t* gB = wB + (long)(n0 + wave * 16 + lr) * H_DIM + cl;

#define STA(sl, kt) do { \
        gll16(gA + (long)(kt) * 32,                &sA[sl][wave * 16][0]); \
        gll16(gA + 128L * H_DIM + (long)(kt) * 32, &sA[sl][128 + wave * 16][0]); } while (0)
#define STB(sl, kt) do { \
        gll16(gB + (long)(kt) * 32,                &sB[sl][wave * 16][0]); \
        gll16(gB + 128L * H_DIM + (long)(kt) * 32, &sB[sl][128 + wave * 16][0]); } while (0)

    const int q = lane >> 4, r16 = lane & 15;
    const int pc = (q ^ ((r16 >> 1) & 3)) * 8;   // swizzled read chunk

    f32x4 acc[8][4] = {};

    // prologue: stage slots 0,1,2 (12 loads in flight), wait oldest 4 (slot 0)
    STA(0, 0); STB(0, 0);
    STA(1, 1); STB(1, 1);
    STA(2, 2); STB(2, 2);
    asm volatile("s_waitcnt vmcnt(8)" ::: "memory");
    __builtin_amdgcn_s_barrier();
    asm volatile("" ::: "memory");

    #pragma unroll 1
    for (int s = 0; s < 32; ++s) {
        const int sl = s & 3;
        s16x8 af[8], bf[4];
        // ---------- phase 0: read A(8)+B(2), stage A of s+3, MFMA n={0,1} ----------
        #pragma unroll
        for (int m = 0; m < 8; ++m)
            af[m] = *(const s16x8*)&sA[sl][wm * 128 + m * 16 + r16][pc];
        bf[0] = *(const s16x8*)&sB[sl][wn * 64 + 0 * 16 + r16][pc];
        bf[1] = *(const s16x8*)&sB[sl][wn * 64 + 1 * 16 + r16][pc];
        if (s + 3 < 32) STA((s + 3) & 3, s + 3);
        asm volatile("" ::: "memory");
        __builtin_amdgcn_s_barrier();
        asm volatile("" ::: "memory");
        __builtin_amdgcn_s_setprio(1);
        #pragma unroll
        for (int m = 0; m < 8; ++m) {
            acc[m][0] = __builtin_amdgcn_mfma_f32_16x16x32_bf16(af[m], bf[0], acc[m][0], 0, 0, 0);
            acc[m][1] = __builtin_amdgcn_mfma_f32_16x16x32_bf16(af[m], bf[1], acc[m][1], 0, 0, 0);
        }
        __builtin_amdgcn_s_setprio(0);
        asm volatile("" ::: "memory");
        __builtin_amdgcn_s_barrier();
        asm volatile("" ::: "memory");
        // ---------- phase 1: read B(2), stage B of s+3, counted vmcnt, MFMA n={2,3} ----------
        bf[2] = *(const s16x8*)&sB[sl][wn * 64 + 2 * 16 + r16][pc];
        bf[3] = *(const s16x8*)&sB[sl][wn * 64 + 3 * 16 + r16][pc];
        if (s + 3 < 32) STB((s + 3) & 3, s + 3);
        if (s < 29)      asm volatile("s_waitcnt vmcnt(8)" ::: "memory");  // slot s+1 landed
        else if (s == 29) asm volatile("s_waitcnt vmcnt(4)" ::: "memory");
        else             asm volatile("s_waitcnt vmcnt(0)" ::: "memory");
        __builtin_amdgcn_s_barrier();
        asm volatile("" ::: "memory");
        __builtin_amdgcn_s_setprio(1);
        #pragma unroll
        for (int m = 0; m < 8; ++m) {
            acc[m][2] = __builtin_amdgcn_mfma_f32_16x16x32_bf16(af[m], bf[2], acc[m][2], 0, 0, 0);
            acc[m][3] = __builtin_amdgcn_mfma_f32_16x16x32_bf16(af[m], bf[3], acc[m][3], 0, 0, 0);
        }
        __builtin_amdgcn_s_setprio(0);
        asm volatile("" ::: "memory");
        __builtin_amdgcn_s_barrier();
        asm volatile("" ::: "memory");
    }
#undef STA
#undef STB

    // epilogue: frags n even = g, n odd = u (same i-block) -> register-local silu
    #pragma unroll
    for (int m = 0; m < 8; ++m) {
        #pragma unroll
        for (int rr = 0; rr < 4; ++rr) {
            const int trow = wm * 128 + m * 16 + q * 4 + rr;
            const float gate = sGate[trow];
            const long tglob = t0 + trow;
            #pragma unroll
            for (int p = 0; p < 2; ++p) {
                float g = acc[m][2 * p][rr], u = acc[m][2 * p + 1][rr];
                float h = gate * (g / (1.f + __expf(-g))) * u;
                const int cb = n0 + wn * 64 + p * 32;              // pure-g frag base
                const int i = (((cb & 1023) >> 5) << 4) + r16;     // within-expert i
                hmid[tglob * KDOWN + e * I_DIM + i] = f2bf(h);
            }
        }
    }
}

// ---------------- down GEMM: split-K=4, ATOMIC epilogue (reduce kernel eliminated) ----------------
// GEMM loop = r2-proven BK=64 double-barrier, (256,3), XCD quadrant decode.
// All 4 kz blocks unsafeAtomicAdd their fp32 tile into out (zero-filled by prep).
// Relaxed device-scope HW f32 atomics (global_atomic_add_f32): no fences, no L2
// invalidation (r1's poison was the ACQ_REL acquire, not the atomic itself).
// Removes: reduce launch, 24MB parts writes, 32MB parts reads, 8MB reduce write.
__global__ __launch_bounds__(256, 3) void moe_down_kernel(
    const uint16_t* __restrict__ hmid,  // [2048][4096]
    const uint16_t* __restrict__ wdT,   // [1024][4096]
    float* __restrict__ out) {          // [2048][1024] pre-zeroed
    const int bid = blockIdx.x + 8 * (blockIdx.y + 16 * blockIdx.z);
    const int r  = bid & 7;             // XCD
    const int j  = bid >> 3;            // 0..63
    const int h0 = ((r & 1) * 4 + (j & 3)) * 128;
    const int t0 = ((r >> 1) * 4 + ((j >> 2) & 3)) * 128;
    const int kz = j >> 4;              // 0..3
    const int kst = kz * 1024;
    __shared__ uint16_t sA[128][64];
    __shared__ uint16_t sB[128][64];
    const int tid  = threadIdx.x;
    const int lane = tid & 63;
    const int wave = tid >> 6;
    const int wm = wave >> 1, wn = wave & 1;

    const int srow = wave * 32 + (lane >> 3);
    const int scol = ((lane & 7) ^ (srow & 7)) * 8;
    const uint16_t* ga = hmid + (long)(t0 + srow) * KDOWN + scol;
    const uint16_t* gb = wdT  + (long)(h0 + srow) * KDOWN + scol;

    f32x4 acc[4][4] = {};
    const int q = lane >> 4, r16 = lane & 15;
    const int sw = r16 & 7;

    for (int kb = kst; kb < kst + 1024; kb += 64) {
        __syncthreads();
        #pragma unroll
        for (int j2 = 0; j2 < 4; ++j2) {
            const int lr = wave * 32 + j2 * 8;
            gll16(ga + (long)j2 * 8 * KDOWN + kb, &sA[lr][0]);
            gll16(gb + (long)j2 * 8 * KDOWN + kb, &sB[lr][0]);
        }
        __syncthreads();
        #pragma unroll
        for (int kk = 0; kk < 2; ++kk) {
            const int pc = ((kk * 4 + q) ^ sw) * 8;
            s16x8 af[4], bf[4];
            #pragma unroll
            for (int m = 0; m < 4; ++m)
                af[m] = *(const s16x8*)&sA[wm * 64 + m * 16 + r16][pc];
            #pragma unroll
            for (int n = 0; n < 4; ++n)
                bf[n] = *(const s16x8*)&sB[wn * 64 + n * 16 + r16][pc];
            #pragma unroll
            for (int m = 0; m < 4; ++m)
                #pragma unroll
                for (int n = 0; n < 4; ++n)
                    acc[m][n] = __builtin_amdgcn_mfma_f32_16x16x32_bf16(af[m], bf[n], acc[m][n], 0, 0, 0);
        }
    }
    #pragma unroll
    for (int m = 0; m < 4; ++m) {
        #pragma unroll
        for (int rr = 0; rr < 4; ++rr) {
            const int t = t0 + wm * 64 + m * 16 + q * 4 + rr;
            #pragma unroll
            for (int n = 0; n < 4; ++n)
                unsafeAtomicAdd(&out[(long)t * H_DIM + h0 + wn * 64 + n * 16 + r16],
                                acc[m][n][rr]);
        }
    }
}

extern "C" void kernel_launch(void* const* d_in, const int* in_sizes, int n_in,
                              void* d_out, int out_size, void* d_ws, size_t ws_size,
                              hipStream_t stream) {
    const float* x    = (const float*)d_in[0];   // [2,1024,1024]
    const float* emb  = (const float*)d_in[1];   // [8,1024]
    const float* thr  = (const float*)d_in[2];   // [8]
    const float* wg   = (const float*)d_in[3];   // [8,1024,512]
    const float* wu   = (const float*)d_in[4];   // [8,1024,512]
    const float* wd   = (const float*)d_in[5];   // [8,512,1024]
    float* out    = (float*)d_out;               // [2048][1024]
    float* scores = out + (size_t)T_TOK * H_DIM; // [2048][8]

    uint8_t* ws = (uint8_t*)d_ws;
    uint16_t* xb   = (uint16_t*)(ws);                         //  4 MB  x bf16
    uint16_t* wB   = (uint16_t*)(ws + (size_t)4  * 1048576);  // 16 MB  [8192][1024] g/u interleaved
    uint16_t* wdT  = (uint16_t*)(ws + (size_t)20 * 1048576);  //  8 MB  [H][E*I]
    uint16_t* hmid = (uint16_t*)(ws + (size_t)28 * 1048576);  // 16 MB  [T][E*I]
    float*    gates = (float*)  (ws + (size_t)44 * 1048576);  // 64 KB  [T][E]

    prep_kernel<<<3072 + T_TOK / 4 + 512, 256, 0, stream>>>(
        wg, wu, wd, wB, wdT, x, emb, thr, scores, gates, xb, out);
    moe_gateup_kernel<<<256, 512, 0, stream>>>(xb, wB, gates, hmid);
    moe_down_kernel<<<dim3(H_DIM / 128, T_TOK / 128, 4), 256, 0, stream>>>(hmid, wdT, out);
}

// Round 9
// 169.363 us; speedup vs baseline: 1.1040x; 1.1040x over previous
//
#include <hip/hip_runtime.h>
#include <hip/hip_bf16.h>
#include <stdint.h>

#define T_TOK 2048
#define H_DIM 1024
#define E_NUM 8
#define I_DIM 512
#define KDOWN (E_NUM * I_DIM) /* 4096 */
#define EPSR 1e-8f

typedef short s16x8 __attribute__((ext_vector_type(8)));
typedef float f32x4 __attribute__((ext_vector_type(4)));

static __device__ __forceinline__ uint16_t f2bf(float f) {
    union { float f; uint32_t i; } v; v.f = f;
    uint32_t lsb = (v.i >> 16) & 1u;
    v.i += 0x7fffu + lsb;                    // round-to-nearest-even
    return (uint16_t)(v.i >> 16);
}

// async global->LDS DMA, 16B/lane; LDS dest = wave-uniform base + lane*16
static __device__ __forceinline__ void gll16(const void* g, void* l) {
    __builtin_amdgcn_global_load_lds(
        (const __attribute__((address_space(1))) void*)g,
        (__attribute__((address_space(3))) void*)l, 16, 0, 0);
}

// ------------- prep: merged weight transpose-cast + routing -------------
// bid<3072: transpose (decoded as old grid (8,16,24)); bid>=3072: routing (512 vblocks)
__global__ __launch_bounds__(256) void prep_kernel(
    const float* __restrict__ wg, const float* __restrict__ wu,
    const float* __restrict__ wd, uint16_t* __restrict__ wgT,
    uint16_t* __restrict__ wuT, uint16_t* __restrict__ wdT,
    const float* __restrict__ x, const float* __restrict__ emb,
    const float* __restrict__ thr, float* __restrict__ scores_out,
    float* __restrict__ gates, uint16_t* __restrict__ xb) {
    __shared__ union {
        float tile[64][69];   // 69: stride 68 was an 8-way bank conflict on col reads; 69 -> 2-way (free)
        struct { float semb[E_NUM * H_DIM]; float senorm[E_NUM]; } r;
    } sm;
    const int bid = blockIdx.x;
    const int tid = threadIdx.x;

    if (bid < 3072) {   // ---- transpose+cast part ----
        const int bz = bid >> 7, by = (bid >> 3) & 15, bx = bid & 7;
        const float* src; uint16_t* dst; int C, out_stride, r0, c0;
        if (bz < 16) {
            const int e = bz & 7;
            src = (bz < 8 ? wg : wu) + (long)e * H_DIM * I_DIM;
            dst = (bz < 8 ? wgT : wuT) + (long)e * I_DIM * H_DIM;
            C = I_DIM; out_stride = H_DIM;
            r0 = by * 64; c0 = bx * 64;
        } else {
            const int e = bz - 16;
            src = wd + (long)e * I_DIM * H_DIM;
            dst = wdT + (long)e * I_DIM;              // wdT[h][e*512 + i]
            C = H_DIM; out_stride = KDOWN;
            r0 = bx * 64; c0 = by * 64;
        }
        const int g16 = tid >> 4, l16 = (tid & 15) * 4;
        #pragma unroll
        for (int it = 0; it < 4; ++it) {
            int r = it * 16 + g16;
            *(float4*)&sm.tile[r][l16] = *(const float4*)(src + (long)(r0 + r) * C + c0 + l16);
        }
        __syncthreads();
        #pragma unroll
        for (int it = 0; it < 4; ++it) {
            int oc = it * 16 + g16;
            ushort4 o;
            o.x = f2bf(sm.tile[l16 + 0][oc]);
            o.y = f2bf(sm.tile[l16 + 1][oc]);
            o.z = f2bf(sm.tile[l16 + 2][oc]);
            o.w = f2bf(sm.tile[l16 + 3][oc]);
            *(ushort4*)(dst + (long)(c0 + oc) * out_stride + r0 + l16) = o;
        }
        return;
    }
    // ---- routing part: cosine scores + masked softmax gates + bf16 cast of x ----
    const int rb = bid - 3072;
    const int lane = tid & 63;
    const int wave = tid >> 6;
    for (int i = tid; i < E_NUM * H_DIM; i += 256) sm.r.semb[i] = emb[i];
    __syncthreads();
    for (int e = wave; e < E_NUM; e += 4) {
        float s = 0.f;
        #pragma unroll
        for (int c = 0; c < 16; ++c) { float v = sm.r.semb[e * H_DIM + lane + 64 * c]; s += v * v; }
        #pragma unroll
        for (int off = 32; off; off >>= 1) s += __shfl_xor(s, off);
        if (lane == 0) sm.r.senorm[e] = fmaxf(sqrtf(s), EPSR);
    }
    __syncthreads();
    const int t = rb * 4 + wave;
    const float* xt = x + (long)t * H_DIM;
    uint16_t* xbt = xb + (long)t * H_DIM;
    float nrm = 0.f, dot[E_NUM];
    #pragma unroll
    for (int e = 0; e < E_NUM; ++e) dot[e] = 0.f;
    #pragma unroll
    for (int c = 0; c < 16; ++c) {
        float v = xt[lane + 64 * c];
        xbt[lane + 64 * c] = f2bf(v);
        nrm += v * v;
        #pragma unroll
        for (int e = 0; e < E_NUM; ++e) dot[e] += v * sm.r.semb[e * H_DIM + lane + 64 * c];
    }
    #pragma unroll
    for (int off = 32; off; off >>= 1) {
        nrm += __shfl_xor(nrm, off);
        #pragma unroll
        for (int e = 0; e < E_NUM; ++e) dot[e] += __shfl_xor(dot[e], off);
    }
    float xn = fmaxf(sqrtf(nrm), EPSR);
    float sc[E_NUM], sel[E_NUM];
    float msel = -1e30f, mall = -1e30f;
    int nsel = 0, arg = 0;
    #pragma unroll
    for (int e = 0; e < E_NUM; ++e) {
        sc[e] = dot[e] / (xn * sm.r.senorm[e]);
        float d = sc[e] - thr[e];
        sel[e] = (d > 0.f) ? 1.f : 0.f;                 // silu(d) > 0  <=>  d > 0
        if (d > 0.f) { nsel++; msel = fmaxf(msel, sc[e]); }
        if (sc[e] > mall) { mall = sc[e]; arg = e; }
    }
    float w[E_NUM], den = 0.f;
    #pragma unroll
    for (int e = 0; e < E_NUM; ++e) { w[e] = (sel[e] > 0.f) ? __expf(sc[e] - msel) : 0.f; den += w[e]; }
    if (lane == 0) {
        #pragma unroll
        for (int e = 0; e < E_NUM; ++e) {
            scores_out[t * E_NUM + e] = sc[e];
            gates[t * E_NUM + e] = (nsel > 0) ? (w[e] / den) : ((e == arg) ? 1.f : 0.f);
        }
    }
}

// ---------------- gate/up GEMM + silu*up*gate -> Hmid bf16 (r2 champion version) ----------------
// grid volume 512; XCD-aware decode: XCD = bid%8 owns ONE expert e => its 2 MB of
// wgT/wuT panels are fetched by a single XCD (1x) instead of all 8 (8x).
// 4 waves 2x2, wave-tile 64x64 DUAL. (256,2): dual accumulator needs ~190 VGPRs;
// forcing 3 waves/SIMD spilled to scratch. NOTE (r3-r8): ring/8-phase variants of
// this kernel measured 42-58us cross-session vs this one's stable 53.4/53.5;
// totals favored THIS version (170.8 champion) — schedule front closed.
__global__ __launch_bounds__(256, 2) void moe_gateup_kernel(
    const uint16_t* __restrict__ xb,    // [2048][1024]
    const uint16_t* __restrict__ wgT,   // [8][512][1024]
    const uint16_t* __restrict__ wuT,   // [8][512][1024]
    const float* __restrict__ gates,    // [2048][8]
    uint16_t* __restrict__ hmid) {      // [2048][4096] = [t][e*512+i]
    const int bid = blockIdx.x + 16 * (blockIdx.y + 4 * blockIdx.z);
    const int e  = bid & 7;             // XCD-resident expert
    const int j  = bid >> 3;            // 0..63
    const int t0 = (j & 15) * 128;
    const int i0 = (j >> 4) * 128;
    __shared__ uint16_t sA[128][64];
    __shared__ uint16_t sG[128][64];
    __shared__ uint16_t sU[128][64];
    __shared__ float sGate[128];
    const int tid  = threadIdx.x;
    const int lane = tid & 63;
    const int wave = tid >> 6;
    const int wm = wave >> 1, wn = wave & 1;
    if (tid < 128) sGate[tid] = gates[(t0 + tid) * E_NUM + e];

    const int srow = wave * 32 + (lane >> 3);
    const int scol = ((lane & 7) ^ (srow & 7)) * 8;   // XOR-swizzled chunk
    const uint16_t* ga = xb  + (long)(t0 + srow) * H_DIM + scol;
    const uint16_t* gg = wgT + ((long)e * I_DIM + i0 + srow) * H_DIM + scol;
    const uint16_t* gu = wuT + ((long)e * I_DIM + i0 + srow) * H_DIM + scol;

    f32x4 accg[4][4] = {}, accu[4][4] = {};
    const int q = lane >> 4, r16 = lane & 15;
    const int sw = r16 & 7;

    for (int kb = 0; kb < H_DIM; kb += 64) {
        __syncthreads();
        #pragma unroll
        for (int j2 = 0; j2 < 4; ++j2) {
            const int lr = wave * 32 + j2 * 8;
            gll16(ga + (long)j2 * 8 * H_DIM + kb, &sA[lr][0]);
            gll16(gg + (long)j2 * 8 * H_DIM + kb, &sG[lr][0]);
            gll16(gu + (long)j2 * 8 * H_DIM + kb, &sU[lr][0]);
        }
        __syncthreads();
        #pragma unroll
        for (int kk = 0; kk < 2; ++kk) {
            const int pc = ((kk * 4 + q) ^ sw) * 8;
            s16x8 af[4], gf[4], uf[4];
            #pragma unroll
            for (int m = 0; m < 4; ++m)
                af[m] = *(const s16x8*)&sA[wm * 64 + m * 16 + r16][pc];
            #pragma unroll
            for (int n = 0; n < 4; ++n) {
                gf[n] = *(const s16x8*)&sG[wn * 64 + n * 16 + r16][pc];
                uf[n] = *(const s16x8*)&sU[wn * 64 + n * 16 + r16][pc];
            }
            #pragma unroll
            for (int m = 0; m < 4; ++m)
                #pragma unroll
                for (int n = 0; n < 4; ++n) {
                    accg[m][n] = __builtin_amdgcn_mfma_f32_16x16x32_bf16(af[m], gf[n], accg[m][n], 0, 0, 0);
                    accu[m][n] = __builtin_amdgcn_mfma_f32_16x16x32_bf16(af[m], uf[n], accu[m][n], 0, 0, 0);
                }
        }
    }
    #pragma unroll
    for (int m = 0; m < 4; ++m) {
        #pragma unroll
        for (int rr = 0; rr < 4; ++rr) {
            const int trow = wm * 64 + m * 16 + q * 4 + rr;
            const float gate = sGate[trow];
            const long base = (long)(t0 + trow) * KDOWN + e * I_DIM + i0;
            #pragma unroll
            for (int n = 0; n < 4; ++n) {
                float g = accg[m][n][rr], u = accu[m][n][rr];
                float h = gate * (g / (1.f + __expf(-g))) * u;
                hmid[base + wn * 64 + n * 16 + r16] = f2bf(h);
            }
        }
    }
}

// ---------------- down GEMM: split-K=4; kz0 -> out, kz1..3 -> fp32 partials ----------------
// r2 champion version: XCD-aware quadrant decode (per-XCD working set 4MB wdT +
// 4MB hmid), BK=64, __syncthreads double-barrier loop, (256,3) occupancy.
// Closed fronts (kept for the record): 2-phase ring @2blk/CU = +5us (r7);
// atomic epilogue = +9-14us (r8); single-barrier ring = +12us (r4/r5).
__global__ __launch_bounds__(256, 3) void moe_down_kernel(
    const uint16_t* __restrict__ hmid,  // [2048][4096]
    const uint16_t* __restrict__ wdT,   // [1024][4096]
    float* __restrict__ out,            // [2048][1024]
    float* __restrict__ parts) {        // [3][2048][1024]
    const int bid = blockIdx.x + 8 * (blockIdx.y + 16 * blockIdx.z);
    const int r  = bid & 7;             // XCD
    const int j  = bid >> 3;            // 0..63
    const int h0 = ((r & 1) * 4 + (j & 3)) * 128;
    const int t0 = ((r >> 1) * 4 + ((j >> 2) & 3)) * 128;
    const int kz = j >> 4;              // 0..3
    const int kst = kz * 1024;
    __shared__ uint16_t sA[128][64];
    __shared__ uint16_t sB[128][64];
    const int tid  = threadIdx.x;
    const int lane = tid & 63;
    const int wave = tid >> 6;
    const int wm = wave >> 1, wn = wave & 1;

    const int srow = wave * 32 + (lane >> 3);
    const int scol = ((lane & 7) ^ (srow & 7)) * 8;
    const uint16_t* ga = hmid + (long)(t0 + srow) * KDOWN + scol;
    const uint16_t* gb = wdT  + (long)(h0 + srow) * KDOWN + scol;

    f32x4 acc[4][4] = {};
    const int q = lane >> 4, r16 = lane & 15;
    const int sw = r16 & 7;

    for (int kb = kst; kb < kst + 1024; kb += 64) {
        __syncthreads();
        #pragma unroll
        for (int j2 = 0; j2 < 4; ++j2) {
            const int lr = wave * 32 + j2 * 8;
            gll16(ga + (long)j2 * 8 * KDOWN + kb, &sA[lr][0]);
            gll16(gb + (long)j2 * 8 * KDOWN + kb, &sB[lr][0]);
        }
        __syncthreads();
        #pragma unroll
        for (int kk = 0; kk < 2; ++kk) {
            const int pc = ((kk * 4 + q) ^ sw) * 8;
            s16x8 af[4], bf[4];
            #pragma unroll
            for (int m = 0; m < 4; ++m)
                af[m] = *(const s16x8*)&sA[wm * 64 + m * 16 + r16][pc];
            #pragma unroll
            for (int n = 0; n < 4; ++n)
                bf[n] = *(const s16x8*)&sB[wn * 64 + n * 16 + r16][pc];
            #pragma unroll
            for (int m = 0; m < 4; ++m)
                #pragma unroll
                for (int n = 0; n < 4; ++n)
                    acc[m][n] = __builtin_amdgcn_mfma_f32_16x16x32_bf16(af[m], bf[n], acc[m][n], 0, 0, 0);
        }
    }
    float* dst = (kz == 0) ? out : (parts + (long)(kz - 1) * T_TOK * H_DIM);
    #pragma unroll
    for (int m = 0; m < 4; ++m) {
        #pragma unroll
        for (int rr = 0; rr < 4; ++rr) {
            const int t = t0 + wm * 64 + m * 16 + q * 4 + rr;
            #pragma unroll
            for (int n = 0; n < 4; ++n)
                dst[(long)t * H_DIM + h0 + wn * 64 + n * 16 + r16] = acc[m][n][rr];
        }
    }
}

// ---------------- reduce: out += part0..part2 ----------------
__global__ __launch_bounds__(256) void reduce_kernel(float* __restrict__ out,
                                                     const float* __restrict__ parts) {
    long i = ((long)blockIdx.x * 256 + threadIdx.x) * 4;
    float4 a = *(const float4*)(out + i);
    #pragma unroll
    for (int j = 0; j < 3; ++j) {
        float4 b = *(const float4*)(parts + (long)j * T_TOK * H_DIM + i);
        a.x += b.x; a.y += b.y; a.z += b.z; a.w += b.w;
    }
    *(float4*)(out + i) = a;
}

extern "C" void kernel_launch(void* const* d_in, const int* in_sizes, int n_in,
                              void* d_out, int out_size, void* d_ws, size_t ws_size,
                              hipStream_t stream) {
    const float* x    = (const float*)d_in[0];   // [2,1024,1024]
    const float* emb  = (const float*)d_in[1];   // [8,1024]
    const float* thr  = (const float*)d_in[2];   // [8]
    const float* wg   = (const float*)d_in[3];   // [8,1024,512]
    const float* wu   = (const float*)d_in[4];   // [8,1024,512]
    const float* wd   = (const float*)d_in[5];   // [8,512,1024]
    float* out    = (float*)d_out;               // [2048][1024]
    float* scores = out + (size_t)T_TOK * H_DIM; // [2048][8]

    uint8_t* ws = (uint8_t*)d_ws;
    uint16_t* xb   = (uint16_t*)(ws);                         //  4 MB  x bf16
    uint16_t* wgT  = (uint16_t*)(ws + (size_t)4  * 1048576);  //  8 MB  [E][I][H]
    uint16_t* wuT  = (uint16_t*)(ws + (size_t)12 * 1048576);  //  8 MB  [E][I][H]
    uint16_t* wdT  = (uint16_t*)(ws + (size_t)20 * 1048576);  //  8 MB  [H][E*I]
    uint16_t* hmid = (uint16_t*)(ws + (size_t)28 * 1048576);  // 16 MB  [T][E*I]
    float*    gates = (float*)  (ws + (size_t)44 * 1048576);  // 64 KB  [T][E]
    float*    parts = (float*)  (ws + (size_t)48 * 1048576);  // 24 MB  [3][T][H]

    prep_kernel<<<3072 + T_TOK / 4, 256, 0, stream>>>(
        wg, wu, wd, wgT, wuT, wdT, x, emb, thr, scores, gates, xb);
    moe_gateup_kernel<<<dim3(T_TOK / 128, I_DIM / 128, E_NUM), 256, 0, stream>>>(
        xb, wgT, wuT, gates, hmid);
    moe_down_kernel<<<dim3(H_DIM / 128, T_TOK / 128, 4), 256, 0, stream>>>(hmid, wdT, out, parts);
    reduce_kernel<<<(T_TOK * H_DIM) / 1024, 256, 0, stream>>>(out, parts);
}